// Round 11
// baseline (27.736 us; speedup 1.0000x reference)
//
#include <hip/hip_runtime.h>

// Problem constants (fixed by the reference setup)
#define BB 8
#define LL 4096
#define DD 1024
#define KK 2048

#define RPB 64              // output rows per block
#define TPB 1024            // threads per block (16 waves)
#define NWORDS (LL / 64)    // 64 u64 words per batch bitmap

typedef float f32x4 __attribute__((ext_vector_type(4)));

// Fused kernel, 256 blocks x 1024 threads (1 block/CU, 16 waves).
// R10 structure (cached loads, NT stores); preamble instances halved again,
// 256 KB contiguous output region per block.
//  1) bitmap: 4 coalesced dword loads + __ballot -> 64 u64 words in LDS,
//  2) wave 0 prefix-scans the 64 popcounts,
//  3) threads 0-63 binary-search their output row: k-th set bit if
//     k < num_tokens else (k-num_tokens)-th clear bit == stable compaction
//     order of argsort(i + (~bm)*L)[:K] (unique keys),
//  4) copy 64 rows x 4 KiB in two phases of (8 loads -> 8 NT stores);
//     next_mask written by threads 0-63.
__global__ void __launch_bounds__(TPB)
fused_gather_kernel(const f32x4* __restrict__ src,
                    const int* __restrict__ bm,
                    f32x4* __restrict__ dst,
                    float* __restrict__ om) {
    __shared__ unsigned long long words[NWORDS];
    __shared__ int pre[NWORDS];     // popcounts, then inclusive prefix
    __shared__ int srows[RPB];

    const int blk   = blockIdx.x;          // 0 .. 255
    const int tid   = threadIdx.x;         // 0 .. 1023
    const int lane  = tid & 63;
    const int wave  = tid >> 6;            // 0 .. 15
    const int b     = blk >> 5;            // 32 blocks per batch
    const int kbase = (blk & 31) * RPB;    // k offset within batch

    const int* m = bm + (size_t)b * LL;

    // 1) bitmap: ballot j in wave w covers positions (j*16+w)*64 + lane
#pragma unroll
    for (int j = 0; j < 4; ++j) {
        const unsigned long long w = __ballot(m[j * TPB + tid] != 0);
        if (lane == 0) {
            const int wi = j * 16 + wave;
            words[wi] = w;
            pre[wi]   = __popcll(w);
        }
    }
    __syncthreads();

    // 2) inclusive scan of 64 word-popcounts (wave 0)
    if (wave == 0) {
        int v = pre[lane];
#pragma unroll
        for (int off = 1; off < 64; off <<= 1) {
            const int t = __shfl_up(v, off, 64);
            if (lane >= off) v += t;
        }
        pre[lane] = v;
    }
    __syncthreads();

    const int total = pre[NWORDS - 1];     // num_tokens for batch b

    // 3) per-row source index selection (threads 0..63)
    if (tid < RPB) {
        const int kb = kbase + tid;
        int lo = 0, hi = NWORDS - 1, r;
        unsigned long long x;
        if (kb < total) {
            // smallest word w with pre[w] > kb
            while (lo < hi) { const int mid = (lo + hi) >> 1; if (pre[mid] > kb) hi = mid; else lo = mid + 1; }
            r = kb - ((lo == 0) ? 0 : pre[lo - 1]);
            x = words[lo];
        } else {
            // clear-bit select: zeros_incl[w] = (w+1)*64 - pre[w]
            const int rz = kb - total;
            while (lo < hi) { const int mid = (lo + hi) >> 1; if ((mid + 1) * 64 - pre[mid] > rz) hi = mid; else lo = mid + 1; }
            r = rz - (lo * 64 - ((lo == 0) ? 0 : pre[lo - 1]));
            x = ~words[lo];
        }
        // select r-th (0-based) set bit of x
        int pos = 0;
#pragma unroll
        for (int sh = 32; sh >= 1; sh >>= 1) {
            const int c = __popcll(x & ((1ull << sh) - 1ull));
            if (r >= c) { r -= c; x >>= sh; pos += sh; }
        }
        srows[tid] = lo * 64 + pos;
        om[(size_t)b * KK + kb] = (kb < total) ? 1.0f : 0.0f;
    }
    __syncthreads();

    // 4) copy: 2 phases x (8 steps x 4 rows); tid>>8 = row quarter, tid&255 = col
    const int quarter = tid >> 8;          // 0 .. 3
    const int col     = tid & 255;
    const size_t srcbase = (size_t)b * LL * (DD / 4);
    f32x4* d = dst + ((size_t)b * KK + kbase + quarter) * (DD / 4) + col;
#pragma unroll
    for (int ph = 0; ph < 2; ++ph) {
        f32x4 v[8];
#pragma unroll
        for (int j = 0; j < 8; ++j)
            v[j] = src[srcbase + (size_t)srows[(ph * 8 + j) * 4 + quarter] * (DD / 4) + col];
#pragma unroll
        for (int j = 0; j < 8; ++j)
            __builtin_nontemporal_store(v[j], &d[(size_t)((ph * 8 + j) * 4) * (DD / 4)]);
    }
}

extern "C" void kernel_launch(void* const* d_in, const int* in_sizes, int n_in,
                              void* d_out, int out_size, void* d_ws, size_t ws_size,
                              hipStream_t stream) {
    const float* hs = (const float*)d_in[0];   // (B, L, D) f32
    const int*   bm = (const int*)d_in[1];     // (B, L) bool -> int32
    // d_in[2] (mask) unused; d_in[3] (next_max_seqlen) fixed at K=2048

    float* out_hs   = (float*)d_out;                        // B*K*D floats
    float* out_mask = (float*)d_out + (size_t)BB * KK * DD; // B*K floats

    fused_gather_kernel<<<(BB * KK) / RPB, TPB, 0, stream>>>(
        (const f32x4*)hs, bm, (f32x4*)out_hs, out_mask);
}

// Round 12
// 27.278 us; speedup vs baseline: 1.0168x; 1.0168x over previous
//
#include <hip/hip_runtime.h>

// Problem constants (fixed by the reference setup)
#define BB 8
#define LL 4096
#define DD 1024
#define KK 2048

#define RPB 32              // output rows per block
#define TPB 1024            // threads per block (16 waves)
#define NWORDS (LL / 64)    // 64 u64 words per batch bitmap

typedef float f32x4 __attribute__((ext_vector_type(4)));

// Fused kernel, 512 blocks x 1024 threads (2 blocks/CU x 16 waves = 32 waves/CU).
// R10 structure (cached loads, NT stores) with the scan->search barrier
// removed: scan, row-search, and mask-write all live in wave 0 (lanes 0-31
// are part of the scan wave), so only 2 block-wide barriers remain.
//  1) bitmap: 4 coalesced dword loads + __ballot -> 64 u64 words in LDS,
//  2) wave 0: shfl prefix-scan of 64 popcounts -> pre[]; lanes 0-31 then
//     binary-search their output row (k-th set bit if k < num_tokens else
//     (k-num_tokens)-th clear bit == stable compaction order of
//     argsort(i + (~bm)*L)[:K], unique keys) and write next_mask,
//  3) copy 32 rows x 4 KiB (8 steps x 4 rows; cached loads, NT stores).
__global__ void __launch_bounds__(TPB)
fused_gather_kernel(const f32x4* __restrict__ src,
                    const int* __restrict__ bm,
                    f32x4* __restrict__ dst,
                    float* __restrict__ om) {
    __shared__ unsigned long long words[NWORDS];
    __shared__ int pre[NWORDS];     // popcounts, then inclusive prefix
    __shared__ int srows[RPB];

    const int blk   = blockIdx.x;          // 0 .. 511
    const int tid   = threadIdx.x;         // 0 .. 1023
    const int lane  = tid & 63;
    const int wave  = tid >> 6;            // 0 .. 15
    const int b     = blk >> 6;            // 64 blocks per batch
    const int kbase = (blk & 63) * RPB;    // k offset within batch

    const int* m = bm + (size_t)b * LL;

    // 1) bitmap: ballot j in wave w covers positions (j*16+w)*64 + lane
#pragma unroll
    for (int j = 0; j < 4; ++j) {
        const unsigned long long w = __ballot(m[j * TPB + tid] != 0);
        if (lane == 0) {
            const int wi = j * 16 + wave;
            words[wi] = w;
            pre[wi]   = __popcll(w);
        }
    }
    __syncthreads();

    // 2) wave 0: scan + row-search + mask write (no intermediate barrier;
    //    pre[] read-after-write within the same wave is lgkmcnt-ordered)
    if (wave == 0) {
        int v = pre[lane];
#pragma unroll
        for (int off = 1; off < 64; off <<= 1) {
            const int t = __shfl_up(v, off, 64);
            if (lane >= off) v += t;
        }
        pre[lane] = v;
        const int total = __shfl(v, 63, 64);   // num_tokens for batch b

        if (lane < RPB) {
            const int kb = kbase + lane;
            int lo = 0, hi = NWORDS - 1, r;
            unsigned long long x;
            if (kb < total) {
                // smallest word w with pre[w] > kb
                while (lo < hi) { const int mid = (lo + hi) >> 1; if (pre[mid] > kb) hi = mid; else lo = mid + 1; }
                r = kb - ((lo == 0) ? 0 : pre[lo - 1]);
                x = words[lo];
            } else {
                // clear-bit select: zeros_incl[w] = (w+1)*64 - pre[w]
                const int rz = kb - total;
                while (lo < hi) { const int mid = (lo + hi) >> 1; if ((mid + 1) * 64 - pre[mid] > rz) hi = mid; else lo = mid + 1; }
                r = rz - (lo * 64 - ((lo == 0) ? 0 : pre[lo - 1]));
                x = ~words[lo];
            }
            // select r-th (0-based) set bit of x
            int pos = 0;
#pragma unroll
            for (int sh = 32; sh >= 1; sh >>= 1) {
                const int c = __popcll(x & ((1ull << sh) - 1ull));
                if (r >= c) { r -= c; x >>= sh; pos += sh; }
            }
            srows[lane] = lo * 64 + pos;
            om[(size_t)b * KK + kb] = (kb < total) ? 1.0f : 0.0f;
        }
    }
    __syncthreads();

    // 3) copy: 8 steps x 4 rows (tid>>8 selects row quarter, tid&255 column)
    const int quarter = tid >> 8;          // 0 .. 3
    const int col     = tid & 255;
    const size_t srcbase = (size_t)b * LL * (DD / 4);
    f32x4 v[8];
#pragma unroll
    for (int j = 0; j < 8; ++j)
        v[j] = src[srcbase + (size_t)srows[j * 4 + quarter] * (DD / 4) + col];
    f32x4* d = dst + ((size_t)b * KK + kbase + quarter) * (DD / 4) + col;
#pragma unroll
    for (int j = 0; j < 8; ++j)
        __builtin_nontemporal_store(v[j], &d[(size_t)(j * 4) * (DD / 4)]);
}

extern "C" void kernel_launch(void* const* d_in, const int* in_sizes, int n_in,
                              void* d_out, int out_size, void* d_ws, size_t ws_size,
                              hipStream_t stream) {
    const float* hs = (const float*)d_in[0];   // (B, L, D) f32
    const int*   bm = (const int*)d_in[1];     // (B, L) bool -> int32
    // d_in[2] (mask) unused; d_in[3] (next_max_seqlen) fixed at K=2048

    float* out_hs   = (float*)d_out;                        // B*K*D floats
    float* out_mask = (float*)d_out + (size_t)BB * KK * DD; // B*K floats

    fused_gather_kernel<<<(BB * KK) / RPB, TPB, 0, stream>>>(
        (const f32x4*)hs, bm, (f32x4*)out_hs, out_mask);
}